// Round 9
// baseline (146.177 us; speedup 1.0000x reference)
//
#include <hip/hip_runtime.h>
#include <math.h>

typedef unsigned short u16;
typedef __bf16 bf16x8 __attribute__((ext_vector_type(8)));
typedef float f32x4 __attribute__((ext_vector_type(4)));

// Problem constants
constexpr int Bc   = 2;
constexpr int Sc   = 4096;
constexpr int HIDc = 768;
constexpr int Hc   = 12;
constexpr int Dc   = 64;
constexpr int Wc   = 128;
constexpr int Mc   = Bc * Sc;

// attention tiling (v5): 128 queries/block, 8 waves, per-wave 18-tile band
constexpr int QT3  = 128;
constexpr int NCT3 = 18;

#define VM_BAR(N) asm volatile("s_waitcnt vmcnt(" #N ")\n\ts_barrier" ::: "memory")
#define BAR()     asm volatile("s_barrier" ::: "memory")

static __device__ __forceinline__ void load_lds16(const void* g, void* l) {
    __builtin_amdgcn_global_load_lds(
        (const __attribute__((address_space(1))) void*)g,
        (__attribute__((address_space(3))) void*)l, 16, 0, 0);
}
static __device__ __forceinline__ u16 to_bf16(float f) {
    return __builtin_bit_cast(u16, (__bf16)f);
}

// ---------------------------------------------------------------------------
// prep: x fp32 -> bf16; block 0 also zero-fills the OOB guard pad.
// ---------------------------------------------------------------------------
__global__ __launch_bounds__(256) void prep_x(const float* __restrict__ x,
                                              u16* __restrict__ xb,
                                              u16* __restrict__ zpad)
{
    int i = blockIdx.x * 256 + threadIdx.x;
    float4 v = ((const float4*)x)[i];
    ushort4 o;
    o.x = to_bf16(v.x); o.y = to_bf16(v.y);
    o.z = to_bf16(v.z); o.w = to_bf16(v.w);
    ((ushort4*)xb)[i] = o;
    if (blockIdx.x == 0 && threadIdx.x < 128)
        ((int4*)zpad)[threadIdx.x] = make_int4(0, 0, 0, 0);  // 2KB zeros
}

// ---------------------------------------------------------------------------
// prep: transpose W [K][N] fp32 -> Wt [N][K] bf16 (z picks q/k/v/d)
// ---------------------------------------------------------------------------
__global__ __launch_bounds__(256) void prep_w(
    const float* __restrict__ Wq, const float* __restrict__ Wk,
    const float* __restrict__ Wv, const float* __restrict__ Wd,
    u16* __restrict__ wqt, u16* __restrict__ wkt,
    u16* __restrict__ wvt, u16* __restrict__ wdt)
{
    const int z = blockIdx.z;
    const float* W = z == 0 ? Wq : z == 1 ? Wk : z == 2 ? Wv : Wd;
    u16* T         = z == 0 ? wqt : z == 1 ? wkt : z == 2 ? wvt : wdt;

    __shared__ float t[32][33];
    const int bx = blockIdx.x * 32, by = blockIdx.y * 32;
    const int tx = threadIdx.x & 31, ty = threadIdx.x >> 5;
#pragma unroll
    for (int i = 0; i < 32; i += 8)
        t[ty + i][tx] = W[(size_t)(by + ty + i) * HIDc + bx + tx];
    __syncthreads();
#pragma unroll
    for (int i = 0; i < 32; i += 8)
        T[(size_t)(bx + ty + i) * HIDc + by + tx] = to_bf16(t[tx][ty + i]);
}

// ---------------------------------------------------------------------------
// BK=32 tile stager: 128 rows x 32 k, pair-row layout [64 pairs][8 slots of
// 16B], swizzle s8 = phys ^ (pair&7). Linear LDS dest, pre-swizzled src.
// 2 loads/thread per matrix -> 4 loads per K-step (vmcnt unit = 4).
// Measured 0 bank conflicts in R5 with this addressing.
// ---------------------------------------------------------------------------
__device__ __forceinline__ void stage32(const u16* __restrict__ M,
                                        int r0, int k0, u16* lds)
{
    const int tid = threadIdx.x;
#pragma unroll
    for (int i = 0; i < 2; ++i) {
        int u    = tid + i * 256;          // 0..511 16B-units
        int pair = u >> 3, phys = u & 7;
        int s8   = phys ^ (pair & 7);
        int row  = 2 * pair + (s8 >> 2);
        int kseg = s8 & 3;
        load_lds16(M + (size_t)(r0 + row) * HIDc + k0 + kseg * 8,
                   (char*)lds + u * 16);
    }
}

// ---------------------------------------------------------------------------
// 128x128 B^T MFMA GEMM core, K=768, BK=32, double-buffered (32KB LDS) with
// COUNTED vmcnt: per iter {STAGE(t+1); vmcnt(4)+bar; ds_read+MFMA(t); bar}.
// stage(t+1)'s 4 loads stay in flight across both barriers (T3/T4).
// 32KB LDS + ~100 VGPR -> ~4 blocks/CU (16 waves/CU) for latency hiding.
// SWAP=0: acc row=m, col=n.  SWAP=1: operands swapped -> row=n, col=m.
// ---------------------------------------------------------------------------
template <int SWAP>
__device__ __forceinline__ void gemm128_core32(
    const u16* __restrict__ A, const u16* __restrict__ Bt,
    int m0, int n0, u16* As, u16* Bs, f32x4 (&acc)[4][4])
{
    const int lane = threadIdx.x & 63, wid = threadIdx.x >> 6;
    const int c16 = lane & 15, g = lane >> 4;
    const int wm = (wid >> 1) * 64, wn = (wid & 1) * 64;

    stage32(A,  m0, 0, As);                // prologue -> buf 0 (4 loads)
    stage32(Bt, n0, 0, Bs);
    int cur = 0;
    for (int t = 0; t < 24; ++t) {
        if (t < 23) {
            stage32(A,  m0, (t + 1) * 32, As + (cur ^ 1) * 4096);
            stage32(Bt, n0, (t + 1) * 32, Bs + (cur ^ 1) * 4096);
            VM_BAR(4);          // stage(t) landed everywhere; stage(t+1) in flight
        } else {
            VM_BAR(0);          // last tile: drain
        }
        const u16* Ab = As + cur * 4096;
        const u16* Bb = Bs + cur * 4096;
        bf16x8 af[4], bfr[4];
#pragma unroll
        for (int tt = 0; tt < 4; ++tt) {
            int ar = wm + tt * 16 + c16;
            int ap = ar >> 1, a8 = (((ar & 1) << 2) | g) ^ (ap & 7);
            af[tt] = *(const bf16x8*)(Ab + ap * 64 + a8 * 8);
            int br = wn + tt * 16 + c16;
            int bp = br >> 1, b8 = (((br & 1) << 2) | g) ^ (bp & 7);
            bfr[tt] = *(const bf16x8*)(Bb + bp * 64 + b8 * 8);
        }
        __builtin_amdgcn_s_setprio(1);
#pragma unroll
        for (int mt = 0; mt < 4; ++mt)
#pragma unroll
            for (int nt = 0; nt < 4; ++nt)
                acc[mt][nt] = SWAP
                    ? __builtin_amdgcn_mfma_f32_16x16x32_bf16(
                          bfr[nt], af[mt], acc[mt][nt], 0, 0, 0)
                    : __builtin_amdgcn_mfma_f32_16x16x32_bf16(
                          af[mt], bfr[nt], acc[mt][nt], 0, 0, 0);
        __builtin_amdgcn_s_setprio(0);
        BAR();                  // all waves done reading buf cur (no vm drain)
        cur ^= 1;
    }
}

// ---------------------------------------------------------------------------
// Merged QKV projection, grid z=0..2 (1152 blocks -> better machine fill,
// xb reused across z via L2).
// z=0/1 (Q,K): SWAP=1 epilogue -> ushort4 store into [B,H,S,D].
// z=2   (V) : SWAP=0 epilogue -> ushort4 store into transposed [B,H,D,S].
// Block-uniform branch; identical barrier structure both paths.
// ---------------------------------------------------------------------------
__global__ __launch_bounds__(256) void gemm_qkv_mfma(
    const u16* __restrict__ xb,
    const u16* __restrict__ wqt, const u16* __restrict__ wkt,
    const u16* __restrict__ wvt,
    const float* __restrict__ bq, const float* __restrict__ bk,
    const float* __restrict__ bv,
    u16* __restrict__ qg, u16* __restrict__ kg, u16* __restrict__ vtg)
{
    __shared__ u16 As[8192], Bs[8192];
    const int z = blockIdx.z;
    const u16* Bt     = z == 0 ? wqt : z == 1 ? wkt : wvt;
    const float* bias = z == 0 ? bq : z == 1 ? bk : bv;

    const int m0 = blockIdx.x * 128, n0 = blockIdx.y * 128;
    f32x4 acc[4][4];
#pragma unroll
    for (int i = 0; i < 4; ++i)
#pragma unroll
        for (int j = 0; j < 4; ++j) acc[i][j] = (f32x4){0.f, 0.f, 0.f, 0.f};

    const int lane = threadIdx.x & 63, wid = threadIdx.x >> 6;
    const int c16 = lane & 15, g = lane >> 4;
    const int wm = (wid >> 1) * 64, wn = (wid & 1) * 64;

    if (z == 2) {
        gemm128_core32<0>(xb, Bt, m0, n0, As, Bs, acc);
        // V epilogue: lane holds 4 consecutive m(=s) at fixed n(=d)
#pragma unroll
        for (int nt = 0; nt < 4; ++nt) {
            int n = n0 + wn + nt * 16 + c16;
            int h = n >> 6, d = n & 63;
            float bn = bias[n];
#pragma unroll
            for (int mt = 0; mt < 4; ++mt) {
                int m = m0 + wm + mt * 16 + g * 4;
                int b = m >> 12, s = m & (Sc - 1);
                size_t base = ((size_t)(b * Hc + h)) * Sc * Dc + (size_t)d * Sc + s;
                ushort4 pk;
                pk.x = to_bf16(acc[mt][nt][0] + bn);
                pk.y = to_bf16(acc[mt][nt][1] + bn);
                pk.z = to_bf16(acc[mt][nt][2] + bn);
                pk.w = to_bf16(acc[mt][nt][3] + bn);
                *(ushort4*)&vtg[base] = pk;
            }
        }
    } else {
        gemm128_core32<1>(xb, Bt, m0, n0, As, Bs, acc);
        // Q/K epilogue: lane holds 4 consecutive n(=d) at fixed m(=s)
        const float scale = z ? 1.0f : 0.125f;
        u16* outp = z ? kg : qg;
#pragma unroll
        for (int mt = 0; mt < 4; ++mt) {
            int m = m0 + wm + mt * 16 + c16;
            int b = m >> 12, s = m & (Sc - 1);
            size_t rowbase = (size_t)(b * Hc) * Sc * Dc + (size_t)s * Dc;
#pragma unroll
            for (int nt = 0; nt < 4; ++nt) {
                int nb = n0 + wn + nt * 16 + g * 4;
                int h = nb >> 6, d0 = nb & 63;
                float4 b4 = *(const float4*)&bias[nb];
                ushort4 pk;
                pk.x = to_bf16((acc[mt][nt][0] + b4.x) * scale);
                pk.y = to_bf16((acc[mt][nt][1] + b4.y) * scale);
                pk.z = to_bf16((acc[mt][nt][2] + b4.z) * scale);
                pk.w = to_bf16((acc[mt][nt][3] + b4.w) * scale);
                *(ushort4*)&outp[rowbase + (size_t)h * Sc * Dc + d0] = pk;
            }
        }
    }
}

// ---------------------------------------------------------------------------
// Output projection + residual (SWAP=1): float4 x-read / y-write.
// ---------------------------------------------------------------------------
__global__ __launch_bounds__(256) void gemm_proj_mfma(
    const u16* __restrict__ ctxb, const u16* __restrict__ wdt,
    const float* __restrict__ bd, const float* __restrict__ x,
    float* __restrict__ y)
{
    __shared__ u16 As[8192], Bs[8192];
    const int m0 = blockIdx.x * 128, n0 = blockIdx.y * 128;
    f32x4 acc[4][4];
#pragma unroll
    for (int i = 0; i < 4; ++i)
#pragma unroll
        for (int j = 0; j < 4; ++j) acc[i][j] = (f32x4){0.f, 0.f, 0.f, 0.f};

    gemm128_core32<1>(ctxb, wdt, m0, n0, As, Bs, acc);

    const int lane = threadIdx.x & 63, wid = threadIdx.x >> 6;
    const int c16 = lane & 15, g = lane >> 4;
    const int wm = (wid >> 1) * 64, wn = (wid & 1) * 64;

#pragma unroll
    for (int mt = 0; mt < 4; ++mt) {
        int m = m0 + wm + mt * 16 + c16;
#pragma unroll
        for (int nt = 0; nt < 4; ++nt) {
            int nb = n0 + wn + nt * 16 + g * 4;
            float4 b4 = *(const float4*)&bd[nb];
            float4 x4 = *(const float4*)&x[(size_t)m * HIDc + nb];
            float4 o4;
            o4.x = acc[mt][nt][0] + b4.x + x4.x;
            o4.y = acc[mt][nt][1] + b4.y + x4.y;
            o4.z = acc[mt][nt][2] + b4.z + x4.z;
            o4.w = acc[mt][nt][3] + b4.w + x4.w;
            *(float4*)&y[(size_t)m * HIDc + nb] = o4;
        }
    }
}

// ---------------------------------------------------------------------------
// MFMA banded attention v5 (unchanged from R8): 128 queries/block, 8 waves,
// 384-row window, per-wave 18-tile band, pm overlays kwin, two-phase PV.
// ---------------------------------------------------------------------------
__global__ __launch_bounds__(512) void band_attn_mfma(
    const u16* __restrict__ qg, const u16* __restrict__ kg,
    const u16* __restrict__ vtg, const u16* __restrict__ zpad,
    u16* __restrict__ ctxb)
{
    extern __shared__ u16 sm[];
    u16* kwin = sm;            // [384][64] (49152B), swizzle seg^(row&7)
    u16* vt   = sm + 24576;    // [64][384], swizzle (sl&~7)|((sl^d)&7)
    u16* pm   = sm;            // [128][192-stride] overlay on kwin

    const int L = blockIdx.x;              // 0..767
    const int xcd = L & 7, tt = L >> 3;    // tt 0..95
    const int hb = xcd * 3 + (tt % 3);     // 0..23
    const int qc = tt / 3;                 // 0..31
    const int h = hb % Hc, b = hb / Hc;

    const int s0 = qc * QT3;
    const int tid = threadIdx.x;
    const int lane = tid & 63, w = tid >> 6;
    const int c16 = lane & 15, g = lane >> 4;
    const size_t hbase = ((size_t)(b * Hc + h)) * Sc * Dc;

    const u16* qp = &qg[hbase + (size_t)(s0 + w * 16 + c16) * Dc + g * 8];
    bf16x8 qa0 = *(const bf16x8*)qp;
    bf16x8 qa1 = *(const bf16x8*)(qp + 32);

#pragma unroll
    for (int i = 0; i < 6; ++i) {
        int c   = i * 8 + w;
        int row = c * 8 + (lane >> 3);
        int seg = (lane & 7) ^ (lane >> 3);
        int pos = s0 - Wc + row;
        const u16* src = (pos >= 0 && pos < Sc)
                       ? &kg[hbase + (size_t)pos * Dc + seg * 8] : zpad;
        load_lds16(src, (char*)kwin + c * 1024 + (lane & 63) * 16);
    }
#pragma unroll
    for (int i = 0; i < 6; ++i) {
        int c   = i * 8 + w;
        int idx = c * 64 + lane;
        int d   = idx / 48;
        int p   = idx - d * 48;
        int seg = (p & ~7) | ((p ^ d) & 7);
        int pos0 = s0 - Wc + seg * 8;
        const u16* src = (pos0 >= 0 && pos0 < Sc)
                       ? &vtg[hbase + (size_t)d * Sc + pos0] : zpad;
        load_lds16(src, (char*)vt + idx * 16);
    }

    VM_BAR(6);   // Q + kwin landed everywhere; vt's 6 loads still in flight

    const int tb  = w & ~1;
    const int off = (w & 1) * 16;
    f32x4 acc[NCT3];
#pragma unroll
    for (int ct = 0; ct < NCT3; ++ct) acc[ct] = (f32x4){0.f, 0.f, 0.f, 0.f};
    __builtin_amdgcn_s_setprio(1);
#pragma unroll
    for (int ct = 0; ct < NCT3; ++ct) {
        int row = (tb + ct) * 16 + c16;
        const u16* kb = kwin + row * 64;
        bf16x8 kb0 = *(const bf16x8*)(kb + (g       ^ (row & 7)) * 8);
        bf16x8 kb1 = *(const bf16x8*)(kb + ((g + 4) ^ (row & 7)) * 8);
        acc[ct] = __builtin_amdgcn_mfma_f32_16x16x32_bf16(qa0, kb0, acc[ct], 0, 0, 0);
        acc[ct] = __builtin_amdgcn_mfma_f32_16x16x32_bf16(qa1, kb1, acc[ct], 0, 0, 0);
    }
    __builtin_amdgcn_s_setprio(0);

    float mrow[4] = {-3e38f, -3e38f, -3e38f, -3e38f};
#pragma unroll
    for (int ct = 0; ct < NCT3; ++ct) {
#pragma unroll
        for (int r = 0; r < 4; ++r) {
            int ql  = g * 4 + r;
            int jl  = ct * 16 + c16 - off;
            int pos = s0 - Wc + (tb + ct) * 16 + c16;
            bool valid = (jl >= ql) && (jl <= ql + 2 * Wc) && (pos >= 0) && (pos < Sc);
            float v = valid ? acc[ct][r] : -3e38f;
            acc[ct][r] = v;
            mrow[r] = fmaxf(mrow[r], v);
        }
    }
#pragma unroll
    for (int r = 0; r < 4; ++r)
#pragma unroll
        for (int o2 = 1; o2 < 16; o2 <<= 1)
            mrow[r] = fmaxf(mrow[r], __shfl_xor(mrow[r], o2));

    float srow[4] = {0.f, 0.f, 0.f, 0.f};
#pragma unroll
    for (int ct = 0; ct < NCT3; ++ct)
#pragma unroll
        for (int r = 0; r < 4; ++r) {
            float e = __expf(acc[ct][r] - mrow[r]);
            acc[ct][r] = e;
            srow[r] += e;
        }
#pragma unroll
    for (int r = 0; r < 4; ++r)
#pragma unroll
        for (int o2 = 1; o2 < 16; o2 <<= 1)
            srow[r] += __shfl_xor(srow[r], o2);

    VM_BAR(0);   // all waves done reading kwin; vt fully landed

    float sq0 = __shfl(srow[0], (c16 >> 2) << 4);
    float sq1 = __shfl(srow[1], (c16 >> 2) << 4);
    float sq2 = __shfl(srow[2], (c16 >> 2) << 4);
    float sq3 = __shfl(srow[3], (c16 >> 2) << 4);
    int rr = c16 & 3;
    float sq = rr == 0 ? sq0 : rr == 1 ? sq1 : rr == 2 ? sq2 : sq3;
    float invq = 1.f / sq;

    const int qrow = w * 16 + c16;
    f32x4 o[4];
#pragma unroll
    for (int dt = 0; dt < 4; ++dt) o[dt] = (f32x4){0.f, 0.f, 0.f, 0.f};

    // ======== PV phase A: tiles 0..9 ========
#pragma unroll
    for (int ct = 0; ct < 10; ++ct)
#pragma unroll
        for (int r = 0; r < 4; ++r) {
            int q   = w * 16 + g * 4 + r;
            int col = ct * 16 + c16;
            int sl  = col >> 3;
            int ph  = (sl & ~7) | ((sl ^ q ^ (q >> 3)) & 7);
            pm[q * 192 + ph * 8 + (col & 7)] = to_bf16(acc[ct][r]);
        }
    __builtin_amdgcn_s_setprio(1);
#pragma unroll
    for (int ks = 0; ks < 5; ++ks) {
        int sl = ks * 4 + g;
        int ph = (sl & ~7) | ((sl ^ qrow ^ (qrow >> 3)) & 7);
        bf16x8 pa = *(const bf16x8*)(pm + qrow * 192 + ph * 8);
#pragma unroll
        for (int dt = 0; dt < 4; ++dt) {
            int d  = dt * 16 + c16;
            int vs = tb * 2 + ks * 4 + g;
            int pv = (vs & ~7) | ((vs ^ d) & 7);
            bf16x8 vb = *(const bf16x8*)(vt + d * 384 + pv * 8);
            o[dt] = __builtin_amdgcn_mfma_f32_16x16x32_bf16(vb, pa, o[dt], 0, 0, 0);
        }
    }
    __builtin_amdgcn_s_setprio(0);

    // ======== PV phase B: tiles 10..17 ========
#pragma unroll
    for (int ct = 10; ct < NCT3; ++ct)
#pragma unroll
        for (int r = 0; r < 4; ++r) {
            int q   = w * 16 + g * 4 + r;
            int col = ct * 16 + c16 - 160;
            int sl  = col >> 3;
            int ph  = (sl & ~7) | ((sl ^ q ^ (q >> 3)) & 7);
            pm[q * 192 + ph * 8 + (col & 7)] = to_bf16(acc[ct][r]);
        }
    __builtin_amdgcn_s_setprio(1);
#pragma unroll
    for (int ks = 0; ks < 4; ++ks) {
        int sl = ks * 4 + g;
        int ph = (sl & ~7) | ((sl ^ qrow ^ (qrow >> 3)) & 7);
        bf16x8 pa = *(const bf16x8*)(pm + qrow * 192 + ph * 8);
#pragma unroll
        for (int dt = 0; dt < 4; ++dt) {
            int d  = dt * 16 + c16;
            int vs = tb * 2 + 20 + ks * 4 + g;
            int pv = (vs & ~7) | ((vs ^ d) & 7);
            bf16x8 vb = *(const bf16x8*)(vt + d * 384 + pv * 8);
            o[dt] = __builtin_amdgcn_mfma_f32_16x16x32_bf16(vb, pa, o[dt], 0, 0, 0);
        }
    }
    __builtin_amdgcn_s_setprio(0);

    const size_t crow = ((size_t)(b * Sc + s0 + qrow)) * HIDc + h * Dc;
#pragma unroll
    for (int dt = 0; dt < 4; ++dt) {
        ushort4 pk;
        pk.x = to_bf16(o[dt][0] * invq);
        pk.y = to_bf16(o[dt][1] * invq);
        pk.z = to_bf16(o[dt][2] * invq);
        pk.w = to_bf16(o[dt][3] * invq);
        *(ushort4*)&ctxb[crow + dt * 16 + g * 4] = pk;
    }
}

// ---------------------------------------------------------------------------
// LayerNorm over last dim (768), block per row
// ---------------------------------------------------------------------------
__global__ __launch_bounds__(256) void ln_kernel(
    const float* __restrict__ y,
    const float* __restrict__ gamma, const float* __restrict__ beta,
    float* __restrict__ out)
{
    const int m = blockIdx.x;
    const float* row = y + (size_t)m * HIDc;
    const int t = threadIdx.x;
    float v0 = row[t], v1 = row[t + 256], v2 = row[t + 512];
    float s = v0 + v1 + v2;
    __shared__ float red[4];
    const int lane = t & 63, wid = t >> 6;
#pragma unroll
    for (int o = 1; o < 64; o <<= 1) s += __shfl_xor(s, o);
    if (lane == 0) red[wid] = s;
    __syncthreads();
    const float mu = (red[0] + red[1] + red[2] + red[3]) * (1.f / HIDc);
    v0 -= mu; v1 -= mu; v2 -= mu;
    float s2 = v0 * v0 + v1 * v1 + v2 * v2;
#pragma unroll
    for (int o = 1; o < 64; o <<= 1) s2 += __shfl_xor(s2, o);
    __syncthreads();
    if (lane == 0) red[wid] = s2;
    __syncthreads();
    const float var = (red[0] + red[1] + red[2] + red[3]) * (1.f / HIDc);
    const float rstd = rsqrtf(var + 1e-12f);
    const size_t base = (size_t)m * HIDc;
    out[base + t]       = v0 * rstd * gamma[t]       + beta[t];
    out[base + t + 256] = v1 * rstd * gamma[t + 256] + beta[t + 256];
    out[base + t + 512] = v2 * rstd * gamma[t + 512] + beta[t + 512];
}

// ---------------------------------------------------------------------------
extern "C" void kernel_launch(void* const* d_in, const int* in_sizes, int n_in,
                              void* d_out, int out_size, void* d_ws, size_t ws_size,
                              hipStream_t stream)
{
    const float* x     = (const float*)d_in[0];
    const float* Wq    = (const float*)d_in[1];
    const float* bq    = (const float*)d_in[2];
    const float* Wk    = (const float*)d_in[3];
    const float* bk    = (const float*)d_in[4];
    const float* Wv    = (const float*)d_in[5];
    const float* bv    = (const float*)d_in[6];
    const float* Wd    = (const float*)d_in[7];
    const float* bd    = (const float*)d_in[8];
    const float* gamma = (const float*)d_in[9];
    const float* beta  = (const float*)d_in[10];
    float* out = (float*)d_out;

    constexpr size_t CHUNK = (size_t)Mc * HIDc;      // 6,291,456
    constexpr size_t WSZ   = (size_t)HIDc * HIDc;    //   589,824
    u16* xb   = (u16*)d_ws;
    u16* wqt  = xb + CHUNK;
    u16* wkt  = wqt + WSZ;
    u16* wvt  = wkt + WSZ;
    u16* wdt  = wvt + WSZ;
    u16* qg   = wdt + WSZ;
    u16* kg   = qg + CHUNK;
    u16* vtg  = kg + CHUNK;
    u16* ctxb = vtg + CHUNK;
    float* yws = (float*)(ctxb + CHUNK);
    u16* zpad  = (u16*)(yws + CHUNK);   // 2KB zero guard (filled by prep_x)

    // 0) precision prep (+ zero guard fill)
    prep_x<<<(CHUNK / 4) / 256, 256, 0, stream>>>(x, xb, zpad);
    prep_w<<<dim3(24, 24, 4), 256, 0, stream>>>(Wq, Wk, Wv, Wd, wqt, wkt, wvt, wdt);

    // 1) merged QKV projections (bf16 MFMA, BK=32 counted-vmcnt dbuf)
    gemm_qkv_mfma<<<dim3(Mc / 128, HIDc / 128, 3), 256, 0, stream>>>(
        xb, wqt, wkt, wvt, bq, bk, bv, qg, kg, vtg);

    // 2) banded attention (v5: 128q/block, 8 waves, 96KB LDS)
    band_attn_mfma<<<dim3(Sc / QT3 * Hc * Bc), 512, 98304, stream>>>(
        qg, kg, vtg, zpad, ctxb);

    // 3) output projection + residual
    gemm_proj_mfma<<<dim3(Mc / 128, HIDc / 128), 256, 0, stream>>>(
        ctxb, wdt, bd, x, yws);

    // 4) LayerNorm
    ln_kernel<<<Mc, 256, 0, stream>>>(yws, gamma, beta, out);
}

// Round 10
// 123.734 us; speedup vs baseline: 1.1814x; 1.1814x over previous
//
#include <hip/hip_runtime.h>
#include <math.h>

typedef unsigned short u16;
typedef __bf16 bf16x8 __attribute__((ext_vector_type(8)));
typedef float f32x4 __attribute__((ext_vector_type(4)));

// Problem constants
constexpr int Bc   = 2;
constexpr int Sc   = 4096;
constexpr int HIDc = 768;
constexpr int Hc   = 12;
constexpr int Dc   = 64;
constexpr int Wc   = 128;
constexpr int Mc   = Bc * Sc;

// attention tiling (v5): 128 queries/block, 8 waves, per-wave 18-tile band
constexpr int QT3  = 128;
constexpr int NCT3 = 18;

#define VM_BAR(N) asm volatile("s_waitcnt vmcnt(" #N ")\n\ts_barrier" ::: "memory")
#define BAR()     asm volatile("s_barrier" ::: "memory")

static __device__ __forceinline__ void load_lds16(const void* g, void* l) {
    __builtin_amdgcn_global_load_lds(
        (const __attribute__((address_space(1))) void*)g,
        (__attribute__((address_space(3))) void*)l, 16, 0, 0);
}
static __device__ __forceinline__ u16 to_bf16(float f) {
    return __builtin_bit_cast(u16, (__bf16)f);
}

// ---------------------------------------------------------------------------
// Fused prep: blocks [0,6144): x fp32 -> bf16 (+ zpad fill in block 0);
// blocks [6144,8448): transpose W [K][N] fp32 -> Wt [N][K] bf16.
// ---------------------------------------------------------------------------
__global__ __launch_bounds__(256) void prep_all(
    const float* __restrict__ x, u16* __restrict__ xb, u16* __restrict__ zpad,
    const float* __restrict__ Wq, const float* __restrict__ Wk,
    const float* __restrict__ Wv, const float* __restrict__ Wd,
    u16* __restrict__ wqt, u16* __restrict__ wkt,
    u16* __restrict__ wvt, u16* __restrict__ wdt)
{
    const int bid = blockIdx.x;
    if (bid < 6144) {
        int i = bid * 256 + threadIdx.x;
        float4 v = ((const float4*)x)[i];
        ushort4 o;
        o.x = to_bf16(v.x); o.y = to_bf16(v.y);
        o.z = to_bf16(v.z); o.w = to_bf16(v.w);
        ((ushort4*)xb)[i] = o;
        if (bid == 0 && threadIdx.x < 128)
            ((int4*)zpad)[threadIdx.x] = make_int4(0, 0, 0, 0);  // 2KB zeros
    } else {
        int r = bid - 6144;                 // 0..2303
        int z = r / 576, xy = r - z * 576;  // 576 = 24*24 tiles per matrix
        const float* W = z == 0 ? Wq : z == 1 ? Wk : z == 2 ? Wv : Wd;
        u16* T         = z == 0 ? wqt : z == 1 ? wkt : z == 2 ? wvt : wdt;
        __shared__ float t[32][33];
        const int bx = (xy % 24) * 32, by = (xy / 24) * 32;
        const int tx = threadIdx.x & 31, ty = threadIdx.x >> 5;
#pragma unroll
        for (int i = 0; i < 32; i += 8)
            t[ty + i][tx] = W[(size_t)(by + ty + i) * HIDc + bx + tx];
        __syncthreads();
#pragma unroll
        for (int i = 0; i < 32; i += 8)
            T[(size_t)(bx + ty + i) * HIDc + by + tx] = to_bf16(t[tx][ty + i]);
    }
}

// ---------------------------------------------------------------------------
// BK=64 tile pair stager: 128 rows x 64 k each for A and B^T.
// Row = 128B = 8 x 16B slots; swizzle slot8 = phys ^ (row&7).
// 8 global_load_lds instructions per wave (4 A + 4 B) -> vmcnt unit = 8.
// ---------------------------------------------------------------------------
__device__ __forceinline__ void stage64(const u16* __restrict__ A,
                                        const u16* __restrict__ Bt,
                                        int m0, int n0, int k0,
                                        u16* As, u16* Bs, int soff)
{
#pragma unroll
    for (int i = 0; i < 4; ++i) {
        int off  = soff + i * 1024;
        int row  = off >> 7;
        int slot = (off >> 4) & 7;
        int seg  = slot ^ (row & 7);
        load_lds16(A  + (size_t)(m0 + row) * HIDc + k0 + seg * 8, (char*)As + off);
        load_lds16(Bt + (size_t)(n0 + row) * HIDc + k0 + seg * 8, (char*)Bs + off);
    }
}

// ---------------------------------------------------------------------------
// 128x128 B^T MFMA GEMM core, K=768, BK=64, double-buffered (64KB LDS) with
// COUNTED vmcnt: per iter {STAGE(t+1); vmcnt(8)+bar; ds_read+MFMA(t); bar}.
// stage(t+1)'s 8 loads stay in flight across both barriers (T3/T4).
// SWAP=0: acc row=m, col=n.  SWAP=1: operands swapped -> row=n, col=m.
// (This is the R6/R8 core — best measured structure for this problem;
//  R9's BK=32 variant regressed: 2x barrier crossings per MFMA.)
// ---------------------------------------------------------------------------
template <int SWAP>
__device__ __forceinline__ void gemm128_core(
    const u16* __restrict__ A, const u16* __restrict__ Bt,
    int m0, int n0, u16* As, u16* Bs, f32x4 (&acc)[4][4])
{
    const int lane = threadIdx.x & 63, wid = threadIdx.x >> 6;
    const int c16 = lane & 15, g = lane >> 4;
    const int wm = (wid >> 1) * 64, wn = (wid & 1) * 64;
    const int soff = wid * 4096 + lane * 16;   // within one 16KB tile

    stage64(A, Bt, m0, n0, 0, As, Bs, soff);   // prologue -> buf 0
    int cur = 0;
    for (int t = 0; t < 12; ++t) {
        if (t < 11) {
            stage64(A, Bt, m0, n0, (t + 1) * 64,
                    As + (cur ^ 1) * 8192, Bs + (cur ^ 1) * 8192, soff);
            VM_BAR(8);          // stage(t) landed everywhere; stage(t+1) in flight
        } else {
            VM_BAR(0);          // last tile: drain
        }
        const u16* Ab = As + cur * 8192;
        const u16* Bb = Bs + cur * 8192;
#pragma unroll
        for (int kk = 0; kk < 2; ++kk) {
            bf16x8 af[4], bfr[4];
#pragma unroll
            for (int tt = 0; tt < 4; ++tt) {
                int ar = wm + tt * 16 + c16;
                int a8 = (kk * 4 + g) ^ (ar & 7);
                af[tt] = *(const bf16x8*)(Ab + ar * 64 + a8 * 8);
                int br = wn + tt * 16 + c16;
                int b8 = (kk * 4 + g) ^ (br & 7);
                bfr[tt] = *(const bf16x8*)(Bb + br * 64 + b8 * 8);
            }
            __builtin_amdgcn_s_setprio(1);
#pragma unroll
            for (int mt = 0; mt < 4; ++mt)
#pragma unroll
                for (int nt = 0; nt < 4; ++nt)
                    acc[mt][nt] = SWAP
                        ? __builtin_amdgcn_mfma_f32_16x16x32_bf16(
                              bfr[nt], af[mt], acc[mt][nt], 0, 0, 0)
                        : __builtin_amdgcn_mfma_f32_16x16x32_bf16(
                              af[mt], bfr[nt], acc[mt][nt], 0, 0, 0);
            __builtin_amdgcn_s_setprio(0);
        }
        BAR();                  // all waves done reading buf cur (no vm drain)
        cur ^= 1;
    }
}

// ---------------------------------------------------------------------------
// Merged QKV projection (z=0..2, 1152 blocks -> full machine in one pass;
// xb reused across z via L2). BK=64 counted-vmcnt core.
// z=0/1 (Q,K): SWAP=1 -> ushort4 store into [B,H,S,D] (Q scaled 1/8).
// z=2   (V) : SWAP=0 -> ushort4 store into transposed [B,H,D,S].
// ---------------------------------------------------------------------------
__global__ __launch_bounds__(256) void gemm_qkv_mfma(
    const u16* __restrict__ xb,
    const u16* __restrict__ wqt, const u16* __restrict__ wkt,
    const u16* __restrict__ wvt,
    const float* __restrict__ bq, const float* __restrict__ bk,
    const float* __restrict__ bv,
    u16* __restrict__ qg, u16* __restrict__ kg, u16* __restrict__ vtg)
{
    __shared__ u16 As[16384], Bs[16384];
    const int z = blockIdx.z;
    const u16* Bt     = z == 0 ? wqt : z == 1 ? wkt : wvt;
    const float* bias = z == 0 ? bq : z == 1 ? bk : bv;

    const int m0 = blockIdx.x * 128, n0 = blockIdx.y * 128;
    f32x4 acc[4][4];
#pragma unroll
    for (int i = 0; i < 4; ++i)
#pragma unroll
        for (int j = 0; j < 4; ++j) acc[i][j] = (f32x4){0.f, 0.f, 0.f, 0.f};

    const int lane = threadIdx.x & 63, wid = threadIdx.x >> 6;
    const int c16 = lane & 15, g = lane >> 4;
    const int wm = (wid >> 1) * 64, wn = (wid & 1) * 64;

    if (z == 2) {
        gemm128_core<0>(xb, Bt, m0, n0, As, Bs, acc);
        // V epilogue: lane holds 4 consecutive m(=s) at fixed n(=d)
#pragma unroll
        for (int nt = 0; nt < 4; ++nt) {
            int n = n0 + wn + nt * 16 + c16;
            int h = n >> 6, d = n & 63;
            float bn = bias[n];
#pragma unroll
            for (int mt = 0; mt < 4; ++mt) {
                int m = m0 + wm + mt * 16 + g * 4;
                int b = m >> 12, s = m & (Sc - 1);
                size_t base = ((size_t)(b * Hc + h)) * Sc * Dc + (size_t)d * Sc + s;
                ushort4 pk;
                pk.x = to_bf16(acc[mt][nt][0] + bn);
                pk.y = to_bf16(acc[mt][nt][1] + bn);
                pk.z = to_bf16(acc[mt][nt][2] + bn);
                pk.w = to_bf16(acc[mt][nt][3] + bn);
                *(ushort4*)&vtg[base] = pk;
            }
        }
    } else {
        gemm128_core<1>(xb, Bt, m0, n0, As, Bs, acc);
        // Q/K epilogue: lane holds 4 consecutive n(=d) at fixed m(=s)
        const float scale = z ? 1.0f : 0.125f;
        u16* outp = z ? kg : qg;
#pragma unroll
        for (int mt = 0; mt < 4; ++mt) {
            int m = m0 + wm + mt * 16 + c16;
            int b = m >> 12, s = m & (Sc - 1);
            size_t rowbase = (size_t)(b * Hc) * Sc * Dc + (size_t)s * Dc;
#pragma unroll
            for (int nt = 0; nt < 4; ++nt) {
                int nb = n0 + wn + nt * 16 + g * 4;
                int h = nb >> 6, d0 = nb & 63;
                float4 b4 = *(const float4*)&bias[nb];
                ushort4 pk;
                pk.x = to_bf16((acc[mt][nt][0] + b4.x) * scale);
                pk.y = to_bf16((acc[mt][nt][1] + b4.y) * scale);
                pk.z = to_bf16((acc[mt][nt][2] + b4.z) * scale);
                pk.w = to_bf16((acc[mt][nt][3] + b4.w) * scale);
                *(ushort4*)&outp[rowbase + (size_t)h * Sc * Dc + d0] = pk;
            }
        }
    }
}

// ---------------------------------------------------------------------------
// Output projection + residual (SWAP=1): float4 x-read / y-write.
// ---------------------------------------------------------------------------
__global__ __launch_bounds__(256) void gemm_proj_mfma(
    const u16* __restrict__ ctxb, const u16* __restrict__ wdt,
    const float* __restrict__ bd, const float* __restrict__ x,
    float* __restrict__ y)
{
    __shared__ u16 As[16384], Bs[16384];
    const int m0 = blockIdx.x * 128, n0 = blockIdx.y * 128;
    f32x4 acc[4][4];
#pragma unroll
    for (int i = 0; i < 4; ++i)
#pragma unroll
        for (int j = 0; j < 4; ++j) acc[i][j] = (f32x4){0.f, 0.f, 0.f, 0.f};

    gemm128_core<1>(ctxb, wdt, m0, n0, As, Bs, acc);

    const int lane = threadIdx.x & 63, wid = threadIdx.x >> 6;
    const int c16 = lane & 15, g = lane >> 4;
    const int wm = (wid >> 1) * 64, wn = (wid & 1) * 64;

#pragma unroll
    for (int mt = 0; mt < 4; ++mt) {
        int m = m0 + wm + mt * 16 + c16;
#pragma unroll
        for (int nt = 0; nt < 4; ++nt) {
            int nb = n0 + wn + nt * 16 + g * 4;
            float4 b4 = *(const float4*)&bd[nb];
            float4 x4 = *(const float4*)&x[(size_t)m * HIDc + nb];
            float4 o4;
            o4.x = acc[mt][nt][0] + b4.x + x4.x;
            o4.y = acc[mt][nt][1] + b4.y + x4.y;
            o4.z = acc[mt][nt][2] + b4.z + x4.z;
            o4.w = acc[mt][nt][3] + b4.w + x4.w;
            *(float4*)&y[(size_t)m * HIDc + nb] = o4;
        }
    }
}

// ---------------------------------------------------------------------------
// MFMA banded attention v5 (unchanged): 128 queries/block, 8 waves,
// 384-row window, per-wave 18-tile band, pm overlays kwin, two-phase PV.
// ---------------------------------------------------------------------------
__global__ __launch_bounds__(512) void band_attn_mfma(
    const u16* __restrict__ qg, const u16* __restrict__ kg,
    const u16* __restrict__ vtg, const u16* __restrict__ zpad,
    u16* __restrict__ ctxb)
{
    extern __shared__ u16 sm[];
    u16* kwin = sm;            // [384][64] (49152B), swizzle seg^(row&7)
    u16* vt   = sm + 24576;    // [64][384], swizzle (sl&~7)|((sl^d)&7)
    u16* pm   = sm;            // [128][192-stride] overlay on kwin

    const int L = blockIdx.x;              // 0..767
    const int xcd = L & 7, tt = L >> 3;    // tt 0..95
    const int hb = xcd * 3 + (tt % 3);     // 0..23
    const int qc = tt / 3;                 // 0..31
    const int h = hb % Hc, b = hb / Hc;

    const int s0 = qc * QT3;
    const int tid = threadIdx.x;
    const int lane = tid & 63, w = tid >> 6;
    const int c16 = lane & 15, g = lane >> 4;
    const size_t hbase = ((size_t)(b * Hc + h)) * Sc * Dc;

    const u16* qp = &qg[hbase + (size_t)(s0 + w * 16 + c16) * Dc + g * 8];
    bf16x8 qa0 = *(const bf16x8*)qp;
    bf16x8 qa1 = *(const bf16x8*)(qp + 32);

#pragma unroll
    for (int i = 0; i < 6; ++i) {
        int c   = i * 8 + w;
        int row = c * 8 + (lane >> 3);
        int seg = (lane & 7) ^ (lane >> 3);
        int pos = s0 - Wc + row;
        const u16* src = (pos >= 0 && pos < Sc)
                       ? &kg[hbase + (size_t)pos * Dc + seg * 8] : zpad;
        load_lds16(src, (char*)kwin + c * 1024 + (lane & 63) * 16);
    }
#pragma unroll
    for (int i = 0; i < 6; ++i) {
        int c   = i * 8 + w;
        int idx = c * 64 + lane;
        int d   = idx / 48;
        int p   = idx - d * 48;
        int seg = (p & ~7) | ((p ^ d) & 7);
        int pos0 = s0 - Wc + seg * 8;
        const u16* src = (pos0 >= 0 && pos0 < Sc)
                       ? &vtg[hbase + (size_t)d * Sc + pos0] : zpad;
        load_lds16(src, (char*)vt + idx * 16);
    }

    VM_BAR(6);   // Q + kwin landed everywhere; vt's 6 loads still in flight

    const int tb  = w & ~1;
    const int off = (w & 1) * 16;
    f32x4 acc[NCT3];
#pragma unroll
    for (int ct = 0; ct < NCT3; ++ct) acc[ct] = (f32x4){0.f, 0.f, 0.f, 0.f};
    __builtin_amdgcn_s_setprio(1);
#pragma unroll
    for (int ct = 0; ct < NCT3; ++ct) {
        int row = (tb + ct) * 16 + c16;
        const u16* kb = kwin + row * 64;
        bf16x8 kb0 = *(const bf16x8*)(kb + (g       ^ (row & 7)) * 8);
        bf16x8 kb1 = *(const bf16x8*)(kb + ((g + 4) ^ (row & 7)) * 8);
        acc[ct] = __builtin_amdgcn_mfma_f32_16x16x32_bf16(qa0, kb0, acc[ct], 0, 0, 0);
        acc[ct] = __builtin_amdgcn_mfma_f32_16x16x32_bf16(qa1, kb1, acc[ct], 0, 0, 0);
    }
    __builtin_amdgcn_s_setprio(0);

    float mrow[4] = {-3e38f, -3e38f, -3e38f, -3e38f};
#pragma unroll
    for (int ct = 0; ct < NCT3; ++ct) {
#pragma unroll
        for (int r = 0; r < 4; ++r) {
            int ql  = g * 4 + r;
            int jl  = ct * 16 + c16 - off;
            int pos = s0 - Wc + (tb + ct) * 16 + c16;
            bool valid = (jl >= ql) && (jl <= ql + 2 * Wc) && (pos >= 0) && (pos < Sc);
            float v = valid ? acc[ct][r] : -3e38f;
            acc[ct][r] = v;
            mrow[r] = fmaxf(mrow[r], v);
        }
    }
#pragma unroll
    for (int r = 0; r < 4; ++r)
#pragma unroll
        for (int o2 = 1; o2 < 16; o2 <<= 1)
            mrow[r] = fmaxf(mrow[r], __shfl_xor(mrow[r], o2));

    float srow[4] = {0.f, 0.f, 0.f, 0.f};
#pragma unroll
    for (int ct = 0; ct < NCT3; ++ct)
#pragma unroll
        for (int r = 0; r < 4; ++r) {
            float e = __expf(acc[ct][r] - mrow[r]);
            acc[ct][r] = e;
            srow[r] += e;
        }
#pragma unroll
    for (int r = 0; r < 4; ++r)
#pragma unroll
        for (int o2 = 1; o2 < 16; o2 <<= 1)
            srow[r] += __shfl_xor(srow[r], o2);

    VM_BAR(0);   // all waves done reading kwin; vt fully landed

    float sq0 = __shfl(srow[0], (c16 >> 2) << 4);
    float sq1 = __shfl(srow[1], (c16 >> 2) << 4);
    float sq2 = __shfl(srow[2], (c16 >> 2) << 4);
    float sq3 = __shfl(srow[3], (c16 >> 2) << 4);
    int rr = c16 & 3;
    float sq = rr == 0 ? sq0 : rr == 1 ? sq1 : rr == 2 ? sq2 : sq3;
    float invq = 1.f / sq;

    const int qrow = w * 16 + c16;
    f32x4 o[4];
#pragma unroll
    for (int dt = 0; dt < 4; ++dt) o[dt] = (f32x4){0.f, 0.f, 0.f, 0.f};

    // ======== PV phase A: tiles 0..9 ========
#pragma unroll
    for (int ct = 0; ct < 10; ++ct)
#pragma unroll
        for (int r = 0; r < 4; ++r) {
            int q   = w * 16 + g * 4 + r;
            int col = ct * 16 + c16;
            int sl  = col >> 3;
            int ph  = (sl & ~7) | ((sl ^ q ^ (q >> 3)) & 7);
            pm[q * 192 + ph * 8 + (col & 7)] = to_bf16(acc[ct][r]);
        }
    __builtin_amdgcn_s_setprio(1);
#pragma unroll
    for (int ks = 0; ks < 5; ++ks) {
        int sl = ks * 4 + g;
        int ph = (sl & ~7) | ((sl ^ qrow ^ (qrow >> 3)) & 7);
        bf16x8 pa = *(const bf16x8*)(pm + qrow * 192 + ph * 8);
#pragma unroll
        for (int dt = 0; dt < 4; ++dt) {
            int d  = dt * 16 + c16;
            int vs = tb * 2 + ks * 4 + g;
            int pv = (vs & ~7) | ((vs ^ d) & 7);
            bf16x8 vb = *(const bf16x8*)(vt + d * 384 + pv * 8);
            o[dt] = __builtin_amdgcn_mfma_f32_16x16x32_bf16(vb, pa, o[dt], 0, 0, 0);
        }
    }
    __builtin_amdgcn_s_setprio(0);

    // ======== PV phase B: tiles 10..17 ========
#pragma unroll
    for (int ct = 10; ct < NCT3; ++ct)
#pragma unroll
        for (int r = 0; r < 4; ++r) {
            int q   = w * 16 + g * 4 + r;
            int col = ct * 16 + c16 - 160;
            int sl  = col >> 3;
            int ph  = (sl & ~7) | ((sl ^ q ^ (q >> 3)) & 7);
            pm[q * 192 + ph * 8 + (col & 7)] = to_bf16(acc[ct][r]);
        }
    __builtin_amdgcn_s_setprio(1);
#pragma unroll
    for (int ks = 0; ks < 4; ++ks) {
        int sl = ks * 4 + g;
        int ph = (sl & ~7) | ((sl ^ qrow ^ (qrow >> 3)) & 7);
        bf16x8 pa = *(const bf16x8*)(pm + qrow * 192 + ph * 8);
#pragma unroll
        for (int dt = 0; dt < 4; ++dt) {
            int d  = dt * 16 + c16;
            int vs = tb * 2 + 20 + ks * 4 + g;
            int pv = (vs & ~7) | ((vs ^ d) & 7);
            bf16x8 vb = *(const bf16x8*)(vt + d * 384 + pv * 8);
            o[dt] = __builtin_amdgcn_mfma_f32_16x16x32_bf16(vb, pa, o[dt], 0, 0, 0);
        }
    }
    __builtin_amdgcn_s_setprio(0);

    const size_t crow = ((size_t)(b * Sc + s0 + qrow)) * HIDc + h * Dc;
#pragma unroll
    for (int dt = 0; dt < 4; ++dt) {
        ushort4 pk;
        pk.x = to_bf16(o[dt][0] * invq);
        pk.y = to_bf16(o[dt][1] * invq);
        pk.z = to_bf16(o[dt][2] * invq);
        pk.w = to_bf16(o[dt][3] * invq);
        *(ushort4*)&ctxb[crow + dt * 16 + g * 4] = pk;
    }
}

// ---------------------------------------------------------------------------
// LayerNorm over last dim (768), block per row
// ---------------------------------------------------------------------------
__global__ __launch_bounds__(256) void ln_kernel(
    const float* __restrict__ y,
    const float* __restrict__ gamma, const float* __restrict__ beta,
    float* __restrict__ out)
{
    const int m = blockIdx.x;
    const float* row = y + (size_t)m * HIDc;
    const int t = threadIdx.x;
    float v0 = row[t], v1 = row[t + 256], v2 = row[t + 512];
    float s = v0 + v1 + v2;
    __shared__ float red[4];
    const int lane = t & 63, wid = t >> 6;
#pragma unroll
    for (int o = 1; o < 64; o <<= 1) s += __shfl_xor(s, o);
    if (lane == 0) red[wid] = s;
    __syncthreads();
    const float mu = (red[0] + red[1] + red[2] + red[3]) * (1.f / HIDc);
    v0 -= mu; v1 -= mu; v2 -= mu;
    float s2 = v0 * v0 + v1 * v1 + v2 * v2;
#pragma unroll
    for (int o = 1; o < 64; o <<= 1) s2 += __shfl_xor(s2, o);
    __syncthreads();
    if (lane == 0) red[wid] = s2;
    __syncthreads();
    const float var = (red[0] + red[1] + red[2] + red[3]) * (1.f / HIDc);
    const float rstd = rsqrtf(var + 1e-12f);
    const size_t base = (size_t)m * HIDc;
    out[base + t]       = v0 * rstd * gamma[t]       + beta[t];
    out[base + t + 256] = v1 * rstd * gamma[t + 256] + beta[t + 256];
    out[base + t + 512] = v2 * rstd * gamma[t + 512] + beta[t + 512];
}

// ---------------------------------------------------------------------------
extern "C" void kernel_launch(void* const* d_in, const int* in_sizes, int n_in,
                              void* d_out, int out_size, void* d_ws, size_t ws_size,
                              hipStream_t stream)
{
    const float* x     = (const float*)d_in[0];
    const float* Wq    = (const float*)d_in[1];
    const float* bq    = (const float*)d_in[2];
    const float* Wk    = (const float*)d_in[3];
    const float* bk    = (const float*)d_in[4];
    const float* Wv    = (const float*)d_in[5];
    const float* bv    = (const float*)d_in[6];
    const float* Wd    = (const float*)d_in[7];
    const float* bd    = (const float*)d_in[8];
    const float* gamma = (const float*)d_in[9];
    const float* beta  = (const float*)d_in[10];
    float* out = (float*)d_out;

    constexpr size_t CHUNK = (size_t)Mc * HIDc;      // 6,291,456
    constexpr size_t WSZ   = (size_t)HIDc * HIDc;    //   589,824
    u16* xb   = (u16*)d_ws;
    u16* wqt  = xb + CHUNK;
    u16* wkt  = wqt + WSZ;
    u16* wvt  = wkt + WSZ;
    u16* wdt  = wvt + WSZ;
    u16* qg   = wdt + WSZ;
    u16* kg   = qg + CHUNK;
    u16* vtg  = kg + CHUNK;
    u16* ctxb = vtg + CHUNK;
    float* yws = (float*)(ctxb + CHUNK);
    u16* zpad  = (u16*)(yws + CHUNK);   // 2KB zero guard (filled by prep_all)

    // 0) fused precision prep (x->bf16, W->Wt bf16, zpad)
    prep_all<<<6144 + 2304, 256, 0, stream>>>(
        x, xb, zpad, Wq, Wk, Wv, Wd, wqt, wkt, wvt, wdt);

    // 1) merged QKV projections (bf16 MFMA, BK=64 counted-vmcnt dbuf)
    gemm_qkv_mfma<<<dim3(Mc / 128, HIDc / 128, 3), 256, 0, stream>>>(
        xb, wqt, wkt, wvt, bq, bk, bv, qg, kg, vtg);

    // 2) banded attention (v5: 128q/block, 8 waves, 96KB LDS)
    band_attn_mfma<<<dim3(Sc / QT3 * Hc * Bc), 512, 98304, stream>>>(
        qg, kg, vtg, zpad, ctxb);

    // 3) output projection + residual
    gemm_proj_mfma<<<dim3(Mc / 128, HIDc / 128), 256, 0, stream>>>(
        ctxb, wdt, bd, x, yws);

    // 4) LayerNorm
    ln_kernel<<<Mc, 256, 0, stream>>>(yws, gamma, beta, out);
}